// Round 15
// baseline (13547.211 us; speedup 1.0000x reference)
//
#include <hip/hip_runtime.h>
#include <stdint.h>

#define N 4096
#define D 1024
#define TILE 512           // rows per tile (8 tiles per round)
#define KL 64              // list length per row
#define THRF 0.25f
#define NEGF (-3.0e38f)
#define GBK 16

// ---- All scratch lives in d_in[0] (16 MB). d_ws never used.
// Numerics invariant (R6..R14-proven): sims = fp32( fp64_fma_chain(d asc)/1024 ),
// ALL comparisons fp32, (val desc, idx asc) — matches np decisions exactly.
// R15: K=64 sorted candidate lists (radix-select spec) make hard collisions
// ~never happen, eliminating the ~4 µs/rescan dirty-remote-L2 floor (R12/R14
// measured). Single-wave walk, consumed set in registers. Lists hold ONLY
// entries >= thr (equivalent: first-unconsumed < thr => no-merge anyway);
// flagK = more-eligible-beyond-list exists.

__global__ void k_init(uint8_t* alive, int* mcnt, int* acnt) {
    int x = blockIdx.x * blockDim.x + threadIdx.x;
    if (x < N) alive[x] = 1;
    if (x < 8) { mcnt[x] = 0; acnt[x] = (x == 0) ? N : 0; }
}

__global__ void k_mgzero(unsigned long long* mgW) {
    if (threadIdx.x < 64) mgW[threadIdx.x] = 0ull;
}

// fp64 LDS-tiled GEMM -> fp32 sim tile; dead rows/cols written as NEGF.
__global__ __launch_bounds__(256) void k_gemm(const float* __restrict__ E,
                                              const uint8_t* __restrict__ alive,
                                              float* __restrict__ simT,
                                              int t0, int bx0) {
    int bi = blockIdx.y;            // row block within tile: 0..7
    int bj = blockIdx.x + bx0;      // column block: bx0..63
    __shared__ float As[64][GBK + 1];
    __shared__ float Bs[64][GBK + 1];
    __shared__ uint8_t alA[64], alB[64];
    int t = threadIdx.x;
    int tr = t >> 4, tc = t & 15;
    if (t < 64) alA[t] = alive[t0 + bi * 64 + t];
    else if (t < 128) alB[t - 64] = alive[bj * 64 + (t - 64)];
    double acc[4][4] = {};
    const float* Arow = E + ((size_t)t0 + (size_t)bi * 64) * D;
    const float* Brow = E + (size_t)bj * 64 * D;
    for (int k0 = 0; k0 < D; k0 += GBK) {
        for (int q = 0; q < 4; ++q) {
            int lin = t + 256 * q;           // 0..1023
            int r = lin >> 4, c = lin & 15;
            As[r][c] = Arow[(size_t)r * D + k0 + c];
            Bs[r][c] = Brow[(size_t)r * D + k0 + c];
        }
        __syncthreads();
        for (int kk = 0; kk < GBK; ++kk) {
            double a[4], b[4];
            for (int u = 0; u < 4; ++u) a[u] = (double)As[tr * 4 + u][kk];
            for (int v = 0; v < 4; ++v) b[v] = (double)Bs[tc * 4 + v][kk];
            for (int u = 0; u < 4; ++u)
                for (int v = 0; v < 4; ++v) acc[u][v] = fma(a[u], b[v], acc[u][v]);
        }
        __syncthreads();
    }
    int rbase = bi * 64 + tr * 4;
    int jbase = bj * 64 + tc * 4;
    for (int u = 0; u < 4; ++u)
        for (int v = 0; v < 4; ++v) {
            float val = (alA[rbase % 64 + u - (rbase % 64 - tr * 4)] && alB[tc * 4 + v])
                        ? (float)(acc[u][v] * (1.0 / 1024.0)) : NEGF;
            // (alA index is just tr*4+u; written verbosely above — simplify:)
            val = (alA[tr * 4 + u] && alB[tc * 4 + v])
                  ? (float)(acc[u][v] * (1.0 / 1024.0)) : NEGF;
            simT[(size_t)(rbase + u) * N + (jbase + v)] = val;
        }
}

// Exact top-64 (val desc, idx asc) of candidates {j>i, !consumed, sim>=thr}.
// Radix-select on fp32 bits (all sims >= 0 -> bit order == value order).
__global__ __launch_bounds__(256) void k_spec(const float* __restrict__ simT,
                                              const unsigned long long* __restrict__ mgW,
                                              int t0,
                                              unsigned long long* __restrict__ listq,
                                              uint8_t* __restrict__ flagK) {
    int r = blockIdx.x;
    int i = t0 + r;
    int t = threadIdx.x;
    __shared__ float sv[N];
    __shared__ unsigned long long mgsh[64];
    __shared__ unsigned int hist[256];
    __shared__ unsigned int pc[256];
    __shared__ unsigned int bufV[KL];
    __shared__ unsigned int bufI[KL];
    __shared__ unsigned int s_cnt, s_pref, s_mask, s_k, s_eqprev, s_cthr;
    const float* row = simT + (size_t)r * N;
    if (t < 64) mgsh[t] = mgW[t];
    if (t == 0) s_cnt = 0;
    __syncthreads();
    unsigned int myThr = 0;
    for (int j = t; j < N; j += 256) {
        float v = row[j];
        bool c = (j > i) && (v >= THRF) && !((mgsh[j >> 6] >> (j & 63)) & 1ull);
        sv[j] = c ? v : NEGF;
        if (c) ++myThr;
    }
    pc[t] = myThr;
    __syncthreads();
    for (int s = 128; s > 0; s >>= 1) { if (t < s) pc[t] += pc[t + s]; __syncthreads(); }
    if (t == 0) s_cthr = pc[0];
    __syncthreads();
    unsigned int cthr = s_cthr;                  // uniform
    if (cthr > KL) {
        if (t == 0) { s_pref = 0; s_mask = 0; s_k = KL; }
        __syncthreads();
        for (int p = 3; p >= 0; --p) {
            hist[t] = 0;
            __syncthreads();
            unsigned int pref = s_pref, msk = s_mask;
            for (int j = t; j < N; j += 256) {
                float v = sv[j];
                if (v >= THRF) {
                    unsigned int key = __float_as_uint(v);
                    if ((key & msk) == pref)
                        atomicAdd(&hist[(key >> (8 * p)) & 0xFF], 1u);
                }
            }
            __syncthreads();
            if (t == 0) {
                unsigned int k = s_k, cum = 0;
                for (int b = 255; b >= 0; --b) {
                    cum += hist[b];
                    if (cum >= k) {
                        s_k = k - (cum - hist[b]);
                        s_pref = pref | ((unsigned)b << (8 * p));
                        s_mask = msk | (0xFFu << (8 * p));
                        break;
                    }
                }
            }
            __syncthreads();
        }
        unsigned int T64 = s_pref;
        unsigned int eqTake = s_k;               // >=1, rank within tie class
        for (int j = t; j < N; j += 256) {       // strictly greater: a = 64-eqTake
            float v = sv[j];
            if (v >= THRF && __float_as_uint(v) > T64) {
                unsigned int pos = atomicAdd(&s_cnt, 1u);
                bufV[pos] = __float_as_uint(v); bufI[pos] = (unsigned)j;
            }
        }
        if (t == 0) s_eqprev = 0;
        __syncthreads();
        for (unsigned int e = 0; e < eqTake; ++e) {   // lowest-idx ties, in order
            unsigned int prev = s_eqprev;
            unsigned int best = 0xFFFFFFFFu;
            for (int j = t; j < N; j += 256) {
                float v = sv[j];
                if (v >= THRF && __float_as_uint(v) == T64 &&
                    (unsigned)j > prev && (unsigned)j < best) best = (unsigned)j;
            }
            pc[t] = best;
            __syncthreads();
            for (int s = 128; s > 0; s >>= 1) { if (t < s) pc[t] = min(pc[t], pc[t + s]); __syncthreads(); }
            if (t == 0) {
                unsigned int pos = s_cnt++;
                bufV[pos] = T64; bufI[pos] = pc[0];
                s_eqprev = pc[0];
            }
            __syncthreads();
        }
    } else {
        for (int j = t; j < N; j += 256) {
            float v = sv[j];
            if (v >= THRF) {
                unsigned int pos = atomicAdd(&s_cnt, 1u);
                bufV[pos] = __float_as_uint(v); bufI[pos] = (unsigned)j;
            }
        }
        __syncthreads();
    }
    if (t < 64) {                                // wave-0 bitonic, desc (val, idx asc)
        unsigned int cnt = s_cnt;
        unsigned long long pack = 0ull;          // sentinel: val=0, idx=0xFFFFFFFF
        if ((unsigned)t < cnt)
            pack = ((unsigned long long)bufV[t] << 32) | (unsigned int)(~bufI[t]);
        unsigned long long sk = ~pack;           // ascending sk == descending pack
        for (int k = 2; k <= 64; k <<= 1)
            for (int j = k >> 1; j > 0; j >>= 1) {
                unsigned long long o = __shfl_xor(sk, j);
                bool lower = ((t & j) == 0);
                bool asc = ((t & k) == 0);
                unsigned long long mn = (sk < o) ? sk : o;
                unsigned long long mx = (sk < o) ? o : sk;
                sk = (asc == lower) ? mn : mx;
            }
        unsigned long long pb = ~sk;
        unsigned int vb = (unsigned int)(pb >> 32);
        unsigned int ix = ~(unsigned int)(pb & 0xFFFFFFFFull);
        listq[(size_t)r * KL + t] = ((unsigned long long)vb << 32) | ix;
    }
    if (t == 0) flagK[r] = (cthr > KL) ? 1 : 0;
}

// Single-wave sequential walk. Consumed bitset in registers (lane L owns cols
// [64L,64L+64)). Per row: one prefetched dwordx2 list load/lane + shfl/ballot.
// Rescan (ballot==0 && flagK): exact full-row argmax vs current state — rare.
__global__ __launch_bounds__(64) void k_walk(const float* __restrict__ simT,
                                             const unsigned long long* __restrict__ listq,
                                             const uint8_t* __restrict__ flagK,
                                             unsigned long long* __restrict__ mgW,
                                             int* __restrict__ partner, int t0,
                                             int* __restrict__ mcnt, int round) {
    int lane = threadIdx.x;
    unsigned long long mw = mgW[lane];
    int nm = 0;
    unsigned long long q0 = listq[lane];
    unsigned long long q1 = listq[KL + lane];
    unsigned char f0 = flagK[0];
    unsigned char f1 = flagK[1];
    for (int r = 0; r < TILE; ++r) {
        unsigned long long cur = q0; unsigned char fb = f0;
        q0 = q1; f0 = f1;
        if (r + 2 < TILE) { q1 = listq[(size_t)(r + 2) * KL + lane]; f1 = flagK[r + 2]; }
        int i = t0 + r;
        unsigned long long iw = __shfl(mw, i >> 6);
        if ((iw >> (i & 63)) & 1ull) { if (lane == 0) partner[i] = -1; continue; }
        unsigned int ix = (unsigned int)cur;
        bool valid = (ix != 0xFFFFFFFFu);
        int jj = valid ? (int)ix : 0;
        unsigned long long jw = __shfl(mw, jj >> 6);
        bool ok = valid && !((jw >> (jj & 63)) & 1ull);
        unsigned long long m = __ballot(ok);
        if (m != 0ull) {
            int f = __ffsll((long long)m) - 1;   // (val desc, idx asc) first
            int pj = __shfl(jj, f);              // list entries all >= thr
            if (lane == (pj >> 6)) mw |= 1ull << (pj & 63);
            if (lane == 0) { partner[i] = pj; ++nm; }
        } else if (fb) {
            const float* row = simT + (size_t)r * N;
            unsigned long long wmask[16];
            #pragma unroll
            for (int k = 0; k < 16; ++k) wmask[k] = __shfl(mw, k * 4 + (lane >> 4));
            int bbase = (lane & 15) * 4;
            float bv = NEGF; int bc = 0x7fffffff;
            #pragma unroll
            for (int k = 0; k < 16; ++k) {
                int cb = k * 256 + 4 * lane;
                float4 qd = *(const float4*)(row + cb);
                unsigned long long w = wmask[k];
                float x0 = (cb + 0 > i && !((w >> (bbase + 0)) & 1ull)) ? qd.x : NEGF;
                float x1 = (cb + 1 > i && !((w >> (bbase + 1)) & 1ull)) ? qd.y : NEGF;
                float x2 = (cb + 2 > i && !((w >> (bbase + 2)) & 1ull)) ? qd.z : NEGF;
                float x3 = (cb + 3 > i && !((w >> (bbase + 3)) & 1ull)) ? qd.w : NEGF;
                float va = (x1 > x0) ? x1 : x0;  int ca = (x1 > x0) ? cb + 1 : cb;
                float vb2 = (x3 > x2) ? x3 : x2; int cd = (x3 > x2) ? cb + 3 : cb + 2;
                float vk = (vb2 > va) ? vb2 : va; int ck = (vb2 > va) ? cd : ca;
                if (vk > bv) { bv = vk; bc = ck; }   // ascending k keeps lower col
            }
            for (int off = 32; off > 0; off >>= 1) {
                float ov = __shfl_down(bv, off);
                int oc = __shfl_down(bc, off);
                if (ov > bv || (ov == bv && oc < bc)) { bv = ov; bc = oc; }
            }
            float bvf = __shfl(bv, 0);
            int bcf = __shfl(bc, 0);
            if (bcf != 0x7fffffff && bvf >= THRF) {
                if (lane == (bcf >> 6)) mw |= 1ull << (bcf & 63);
                if (lane == 0) { partner[i] = bcf; ++nm; }
            } else if (lane == 0) partner[i] = -1;
        } else if (lane == 0) partner[i] = -1;
    }
    mgW[lane] = mw;
    if (lane == 0 && nm) atomicAdd(&mcnt[round], nm);
}

__global__ void k_apply(const unsigned long long* __restrict__ mgW,
                        uint8_t* __restrict__ alive, uint8_t* __restrict__ consumed) {
    int x = blockIdx.x * blockDim.x + threadIdx.x;
    if (x < N) {
        uint8_t m = (uint8_t)((mgW[x >> 6] >> (x & 63)) & 1ull);
        consumed[x] = m;
        alive[x] = (uint8_t)(alive[x] && !m);
    }
}

__global__ __launch_bounds__(256) void k_count(const uint8_t* __restrict__ alive,
                                               int* __restrict__ acnt, int slot) {
    int x = blockIdx.x * 256 + threadIdx.x;
    int lane = threadIdx.x & 63;
    unsigned long long b = __ballot(alive[x] != 0);
    if (lane == 0) atomicAdd(&acnt[slot], (int)__popcll(b));
}

__global__ void k_fuse(float* __restrict__ E, const int* __restrict__ partner) {
    int i = blockIdx.x;
    int p = partner[i];
    if (p < 0) return;
    float* ri = E + (size_t)i * D;
    const float* rp = E + (size_t)p * D;
    for (int e = threadIdx.x; e < D; e += blockDim.x)
        ri[e] = fminf(ri[e] + rp[e], 1.0f);
}

__global__ void k_zero(float* __restrict__ E, const uint8_t* __restrict__ consumed) {
    int i = blockIdx.x;
    if (!consumed[i]) return;
    float* ri = E + (size_t)i * D;
    for (int e = threadIdx.x; e < D; e += blockDim.x) ri[e] = 0.0f;
}

__global__ void k_alive_out(const uint8_t* __restrict__ alive, float* __restrict__ outA) {
    int x = blockIdx.x * blockDim.x + threadIdx.x;
    if (x < N) outA[x] = alive[x] ? 1.0f : 0.0f;
}

// AUDIT: fires ONLY on invariant violation (after+m==before, 2m<=before).
__global__ void k_diag(const int* __restrict__ mcnt, const int* __restrict__ acnt,
                       float* __restrict__ out) {
    bool bad = false;
    for (int r = 0; r < 4; ++r) {
        int before = acnt[r], after = acnt[r + 1], m = mcnt[r];
        if (after + m != before) bad = true;
        if (2 * m > before) bad = true;
        if (m < 0 || m > 2048) bad = true;
    }
    if (bad) out[0] = (float)(8.0e6 + (double)mcnt[0] * 2048.0 + (double)mcnt[1]);
}

extern "C" void kernel_launch(void* const* d_in, const int* in_sizes, int n_in,
                              void* d_out, int out_size, void* d_ws, size_t ws_size,
                              hipStream_t stream) {
    const float* Ein = (const float*)d_in[0];
    float* E = (float*)d_out;                    // 4096*1024 fp32, updated in place
    float* outAlive = E + (size_t)N * D;         // 4096 floats (0/1)

    // arena = d_in[0] after the on-stream copy below (16 MB guaranteed)
    char* ws = (char*)d_in[0];
    float* simT = (float*)ws;      ws += (size_t)TILE * N * 4;          // 8 MB
    unsigned long long* listq = (unsigned long long*)ws;
    ws += (size_t)TILE * KL * 8;                                        // 256 KB
    int* partner = (int*)ws;       ws += (size_t)N * 4;                 // 16 KB
    int* mcnt = (int*)ws;          ws += 8 * 4;
    int* acnt = (int*)ws;          ws += 8 * 4;
    unsigned long long* mgW = (unsigned long long*)ws; ws += 64 * 8;
    uint8_t* flagK = (uint8_t*)ws; ws += TILE;
    uint8_t* alive = (uint8_t*)ws; ws += N;
    uint8_t* consumed = (uint8_t*)ws;            // total ~8.3 MB << 16 MB

    hipMemcpyAsync(E, Ein, (size_t)N * D * sizeof(float), hipMemcpyDeviceToDevice, stream);
    k_init<<<(N + 255) / 256, 256, 0, stream>>>(alive, mcnt, acnt);

    for (int round = 0; round < 4; ++round) {
        k_mgzero<<<1, 64, 0, stream>>>(mgW);
        for (int tile = 0; tile < N / TILE; ++tile) {
            int t0 = tile * TILE;
            int bx0 = t0 / 64;                    // skip never-read columns j < t0
            k_gemm<<<dim3(64 - bx0, TILE / 64), 256, 0, stream>>>(E, alive, simT, t0, bx0);
            k_spec<<<TILE, 256, 0, stream>>>(simT, mgW, t0, listq, flagK);
            k_walk<<<1, 64, 0, stream>>>(simT, listq, flagK, mgW, partner, t0, mcnt, round);
        }
        k_apply<<<(N + 255) / 256, 256, 0, stream>>>(mgW, alive, consumed);
        k_count<<<16, 256, 0, stream>>>(alive, acnt, round + 1);
        k_fuse<<<N, 256, 0, stream>>>(E, partner);
        k_zero<<<N, 256, 0, stream>>>(E, consumed);
    }
    k_alive_out<<<(N + 255) / 256, 256, 0, stream>>>(alive, outAlive);
    k_diag<<<1, 1, 0, stream>>>(mcnt, acnt, E);   // conditional sentinel only
}